// Round 8
// baseline (249.327 us; speedup 1.0000x reference)
//
#include <hip/hip_runtime.h>
#include <hip/hip_bf16.h>

// Problem: B=8, N=1024, D=768, H=12, dh=64. I/O FP32; internal compute bf16 MFMA.
// Pipeline: [0] cvt x,Wq,Wk,Wv,Wo fp32->bf16 into ws
//           [1] QKV gemm: BM=256 BN=128 BK=64, 8 waves, TRI-buffered LDS,
//               counted vmcnt(6) + raw s_barrier, L2-blocked XCD swizzle
//               (round-6 proven 48.5 us) -> q,k [B,H,N,64], vt [B,H,64,N]
//           [2] flash attention, BARRIER-FREE: K and V fragments read DIRECTLY from
//               global (L2-resident: 256 KB/head, XCD-local grid) -- no K/V LDS
//               staging, no double-buffer, no __syncthreads (P buffer is
//               wave-private). SWAPPED QK^T (mfma(K,Q) -> S^T, kv lane-local),
//               packed P via f2b + ds_write_b64 into [32][72]; PV A-frag is one
//               ds_read_b128. ones-MFMA row-sums. LDS 18.4 KB.
//           [3] out gemm: r0-proven 128^2 BK=32 dbuf structure + bias (fp32 out).
// MFMA 16x16x32 bf16. A/B frag: elem(lane&15, k=quad*8+j). C/D: col=lane&15, row=quad*4+r.
// 128B-row LDS swizzle (qkv): granule g of row r stored at g^(r&7).
// 64B-row (BK=32) swizzle (out): granule g of row r at g^((r>>1)&3).

typedef unsigned short u16;
typedef unsigned int u32;
typedef __attribute__((ext_vector_type(8))) short bf8;   // 8 bf16 in 4 VGPRs
typedef __attribute__((ext_vector_type(4))) short bf4;   // 4 bf16 in 2 VGPRs
typedef __attribute__((ext_vector_type(4))) float f4;
typedef __attribute__((ext_vector_type(4))) unsigned short us4;

#define NB 8
#define NSEQ 1024
#define DMODEL 768
#define NHEAD 12
#define DHEAD 64

#define XELEMS   (NB * NSEQ * DMODEL)          // 6291456
#define WELEMS   (DMODEL * DMODEL)             // 589824

__device__ __forceinline__ float b2f(u16 u) {
  union { unsigned int i; float f; } c; c.i = ((unsigned int)u) << 16; return c.f;
}
__device__ __forceinline__ u16 f2b(float f) {
  union { float f; unsigned int i; } c; c.f = f;
  unsigned int r = c.i + 0x7fffu + ((c.i >> 16) & 1u);
  return (u16)(r >> 16);
}
__device__ __forceinline__ void gl_lds16(const u16* g, u16* l) {
  __builtin_amdgcn_global_load_lds(
      (const __attribute__((address_space(1))) unsigned int*)g,
      (__attribute__((address_space(3))) unsigned int*)l, 16, 0, 0);
}

// ---------------- Stage 0: fp32 -> bf16 conversion ----------------
struct CvtArgs {
  const float* src[5];
  u16* dst[5];
};
#define G0 (XELEMS / 4)
#define GW (WELEMS / 4)
#define GTOT (G0 + 4 * GW)

__global__ __launch_bounds__(256) void cvt_kernel(CvtArgs a) {
  size_t g = (size_t)blockIdx.x * 256 + threadIdx.x;
  if (g >= GTOT) return;
  int t; size_t off;
  if (g < G0) { t = 0; off = g; }
  else { size_t r = g - G0; t = 1 + (int)(r / GW); off = r % GW; }
  f4 v = *(const f4*)(a.src[t] + off * 4);
  us4 o;
  o[0] = f2b(v[0]); o[1] = f2b(v[1]); o[2] = f2b(v[2]); o[3] = f2b(v[3]);
  *(us4*)(a.dst[t] + off * 4) = o;
}

// ---------------- Stage 1: QKV projection (BM=256, BN=128, BK=64, tri-buf, counted vmcnt) ----------------
// Round-6 proven version (48.5 us). L2-blocked XCD swizzle.
__global__ __launch_bounds__(512, 2) void qkv_gemm(
    const u16* __restrict__ x, const u16* __restrict__ Wq,
    const u16* __restrict__ Wk, const u16* __restrict__ Wv,
    u16* __restrict__ q, u16* __restrict__ k, u16* __restrict__ vt)
{
  __shared__ __align__(16) u16 lA[3][256 * 64];   // 32 KB x3
  __shared__ __align__(16) u16 lB[3][128 * 64];   // 16 KB x3   total 144 KB

  const int tid  = threadIdx.x;
  const int lane = tid & 63;
  const int w    = tid >> 6;        // 0..7
  const int wm4  = w >> 1;          // 0..3
  const int wn2  = w & 1;           // 0..1
  const int col  = lane & 15;
  const int quad = lane >> 4;

  // L2-blocked XCD swizzle: bid -> (xcd, j); j = bng*24 + bm4*6 + bn6
  const int bid = blockIdx.x;
  const int xcd = bid & 7;
  const int j   = bid >> 3;         // 0..71
  const int bng = j / 24;           // 0..2
  const int bm4 = (j % 24) / 6;     // 0..3
  const int bn6 = j % 6;            // 0..5
  const int bm  = xcd * 4 + bm4;    // 0..31
  const int bn  = bng * 6 + bn6;    // 0..17

  const int m0 = bm * 256;
  const int proj = bn / 6;                      // 0=q,1=k,2=v
  const u16* Wsel = (proj == 0) ? Wq : (proj == 1 ? Wk : Wv);
  const int nrem0 = (bn % 6) * 128;

  const int srow8 = lane >> 3;                  // 0..7
  const int sg    = (lane & 7) ^ srow8;         // pre-swizzled source granule

  const u16* gA = x    + (size_t)(m0    + w * 8 + srow8) * DMODEL + sg * 8;
  const u16* gB = Wsel + (size_t)(nrem0 + w * 8 + srow8) * DMODEL + sg * 8;

  f4 acc[4][4];
#pragma unroll
  for (int i = 0; i < 4; i++)
#pragma unroll
    for (int jj = 0; jj < 4; jj++) acc[i][jj] = (f4)0.0f;

#define QKV_STAGE(T, BUF)                                                      \
  do {                                                                         \
    const int kk_ = (T) * 64;                                                  \
    _Pragma("unroll")                                                          \
    for (int r_ = 0; r_ < 4; r_++)                                             \
      gl_lds16(gA + (size_t)r_ * 64 * DMODEL + kk_,                            \
               &lA[BUF][(r_ * 64 + w * 8) * 64]);                              \
    _Pragma("unroll")                                                          \
    for (int r_ = 0; r_ < 2; r_++)                                             \
      gl_lds16(gB + (size_t)r_ * 64 * DMODEL + kk_,                            \
               &lB[BUF][(r_ * 64 + w * 8) * 64]);                              \
  } while (0)

  QKV_STAGE(0, 0);
  QKV_STAGE(1, 1);

  for (int t = 0; t < 12; t++) {
    if (t < 11) { asm volatile("s_waitcnt vmcnt(6)" ::: "memory"); }
    else        { asm volatile("s_waitcnt vmcnt(0)" ::: "memory"); }
    __builtin_amdgcn_s_barrier();
    asm volatile("" ::: "memory");

    if (t < 10) QKV_STAGE(t + 2, (t + 2) % 3);

    const int buf = t % 3;
    bf8 af[4][2], bfr[4][2];
#pragma unroll
    for (int mt = 0; mt < 4; mt++) {
      const int row = wm4 * 64 + mt * 16 + col;
#pragma unroll
      for (int kt = 0; kt < 2; kt++)
        af[mt][kt] = *(const bf8*)&lA[buf][row * 64 + (((kt * 4 + quad) ^ (row & 7)) << 3)];
    }
#pragma unroll
    for (int nt = 0; nt < 4; nt++) {
      const int row = wn2 * 64 + nt * 16 + col;
#pragma unroll
      for (int kt = 0; kt < 2; kt++)
        bfr[nt][kt] = *(const bf8*)&lB[buf][row * 64 + (((kt * 4 + quad) ^ (row & 7)) << 3)];
    }

    __builtin_amdgcn_s_setprio(1);
#pragma unroll
    for (int mt = 0; mt < 4; mt++)
#pragma unroll
      for (int nt = 0; nt < 4; nt++)
#pragma unroll
        for (int kt = 0; kt < 2; kt++)
          acc[mt][nt] = __builtin_amdgcn_mfma_f32_16x16x32_bf16(af[mt][kt], bfr[nt][kt], acc[mt][nt], 0, 0, 0);
    __builtin_amdgcn_s_setprio(0);
  }
#undef QKV_STAGE

  const int mw0 = m0 + wm4 * 64, nw0 = nrem0 + wn2 * 64;
  if (proj == 2) {
#pragma unroll
    for (int mt = 0; mt < 4; mt++) {
#pragma unroll
      for (int nt = 0; nt < 4; nt++) {
        const int nc = nw0 + nt * 16 + col;
        const int h = nc >> 6, e = nc & 63;
        const int t0 = mw0 + mt * 16 + quad * 4;
        const int b = t0 >> 10, tok0 = t0 & 1023;
        us4 pk;
#pragma unroll
        for (int r = 0; r < 4; r++) pk[r] = f2b(acc[mt][nt][r]);
        *(us4*)(vt + ((size_t)(b * NHEAD + h) * DHEAD + e) * NSEQ + tok0) = pk;
      }
    }
  } else {
    u16* dst = (proj == 0) ? q : k;
#pragma unroll
    for (int mt = 0; mt < 4; mt++) {
#pragma unroll
      for (int nt = 0; nt < 4; nt++) {
        const int nc = nw0 + nt * 16 + col;
        const int h = nc >> 6, e = nc & 63;
#pragma unroll
        for (int r = 0; r < 4; r++) {
          const int t = mw0 + mt * 16 + quad * 4 + r;
          const int b = t >> 10, tok = t & 1023;
          dst[((size_t)(b * NHEAD + h) * NSEQ + tok) * DHEAD + e] = f2b(acc[mt][nt][r]);
        }
      }
    }
  }
}

// ---------------- Stage 2: flash attention (BARRIER-FREE, direct-L2 K/V) ----------------
// 1D grid 768: idx = qc*96 + bh  ->  idx%8 == bh%8, all q-chunks of one (b,h) on one
// XCD (K/V 256 KB/head stays L2-resident). No K/V staging: fragments load straight
// from global (16B/lane, aligned). P buffer is wave-private -> NO __syncthreads.
// S^T = mfma(K, Q): lane holds (q = col, kv = kvt*16 + quad*4 + r); pack 4 bf16 via
// f2b, ONE ds_write_b64 at ldsP[w][q][kv]; PV A-frag = one ds_read_b128.
__global__ __launch_bounds__(256, 3) void attn_kernel(
    const u16* __restrict__ q, const u16* __restrict__ k,
    const u16* __restrict__ vt, u16* __restrict__ attn)
{
  __shared__ __align__(16) u16 ldsP[4][32][72];   // wave-private P [q-row][kv] (18.4 KB)

  const int tid  = threadIdx.x;
  const int lane = tid & 63;
  const int w    = tid >> 6;
  const int col  = lane & 15;
  const int quad = lane >> 4;

  const int idx = blockIdx.x;
  const int bh = idx % 96, qc = idx / 96;
  const int b = bh / 12, h = bh % 12;

  const size_t head = ((size_t)b * NHEAD + h) * NSEQ * DHEAD;  // works for q,k and vt
  const int q0 = qc * 128 + w * 32;

  // ones B-frag for l row-sums via MFMA
  bf8 onesf;
#pragma unroll
  for (int jj = 0; jj < 8; jj++) onesf[jj] = (short)0x3F80;  // bf16 1.0

  // Q fragments, pre-scaled by 1/sqrt(64)=0.125 (exact in bf16)
  bf8 qf[2][2];
#pragma unroll
  for (int qt = 0; qt < 2; qt++)
#pragma unroll
    for (int kt = 0; kt < 2; kt++) {
      const int row = q0 + qt * 16 + col;
      bf8 t = *(const bf8*)(q + head + (size_t)row * DHEAD + kt * 32 + quad * 8);
#pragma unroll
      for (int jj = 0; jj < 8; jj++) t[jj] = (short)f2b(b2f((u16)t[jj]) * 0.125f);
      qf[qt][kt] = t;
    }

  f4 lacc[2];
  f4 o[2][4];
#pragma unroll
  for (int mt = 0; mt < 2; mt++) {
    lacc[mt] = (f4)0.0f;
#pragma unroll
    for (int et = 0; et < 4; et++) o[mt][et] = (f4)0.0f;
  }

  // per-lane K/V fragment base pointers (16B-aligned; only the tile index varies)
  const u16* kb0 = k  + head + (size_t)col * DHEAD + quad * 8;  // + kv*DHEAD + kt*32
  const u16* vb0 = vt + head + (size_t)col * NSEQ + quad * 8;   // + e16*NSEQ + kv + kt2*32

  for (int t = 0; t < NSEQ / 64; t++) {
    const int kv0 = t * 64;

    // S^T = K @ (Q/8)^T  [64 kv x 32 q] per wave; K frags direct from global (L2)
    f4 st[4][2];
#pragma unroll
    for (int kvt = 0; kvt < 4; kvt++)
#pragma unroll
      for (int qt = 0; qt < 2; qt++) st[kvt][qt] = (f4)0.0f;
#pragma unroll
    for (int kt = 0; kt < 2; kt++) {
      bf8 kf[4];
#pragma unroll
      for (int kvt = 0; kvt < 4; kvt++)
        kf[kvt] = *(const bf8*)(kb0 + (size_t)(kv0 + kvt * 16) * DHEAD + kt * 32);
      __builtin_amdgcn_s_setprio(1);
#pragma unroll
      for (int kvt = 0; kvt < 4; kvt++)
#pragma unroll
        for (int qt = 0; qt < 2; qt++)
          st[kvt][qt] = __builtin_amdgcn_mfma_f32_16x16x32_bf16(kf[kvt], qf[qt][kt], st[kvt][qt], 0, 0, 0);
      __builtin_amdgcn_s_setprio(0);
    }

    // P = exp(S): f2b packed in-register, ONE ds_write_b64 per acc (wave-private)
#pragma unroll
    for (int kvt = 0; kvt < 4; kvt++)
#pragma unroll
      for (int qt = 0; qt < 2; qt++) {
        const f4 p = st[kvt][qt];
        bf4 pw;
        pw[0] = (short)f2b(__expf(p[0]));
        pw[1] = (short)f2b(__expf(p[1]));
        pw[2] = (short)f2b(__expf(p[2]));
        pw[3] = (short)f2b(__expf(p[3]));
        *(bf4*)&ldsP[w][qt * 16 + col][kvt * 16 + quad * 4] = pw;
      }
    asm volatile("" ::: "memory");   // order P writes before PV reads (aliasing guard)

    // PV: V frags direct from global (L2); pf = one ds_read_b128
#pragma unroll
    for (int kt2 = 0; kt2 < 2; kt2++) {
      bf8 vf[4];
#pragma unroll
      for (int et = 0; et < 4; et++)
        vf[et] = *(const bf8*)(vb0 + (size_t)(et * 16) * NSEQ + kv0 + kt2 * 32);
#pragma unroll
      for (int mt = 0; mt < 2; mt++) {
        const bf8 pf = *(const bf8*)&ldsP[w][mt * 16 + col][kt2 * 32 + quad * 8];
        __builtin_amdgcn_s_setprio(1);
        lacc[mt] = __builtin_amdgcn_mfma_f32_16x16x32_bf16(pf, onesf, lacc[mt], 0, 0, 0);
#pragma unroll
        for (int et = 0; et < 4; et++)
          o[mt][et] = __builtin_amdgcn_mfma_f32_16x16x32_bf16(pf, vf[et], o[mt][et], 0, 0, 0);
        __builtin_amdgcn_s_setprio(0);
      }
    }
  }

  // epilogue: every lane already holds its row-sum in lacc (all n-cols equal)
#pragma unroll
  for (int mt = 0; mt < 2; mt++)
#pragma unroll
    for (int r = 0; r < 4; r++) {
      const float inv = 1.0f / lacc[mt][r];
      const int token = q0 + mt * 16 + quad * 4 + r;
#pragma unroll
      for (int et = 0; et < 4; et++)
        attn[(size_t)(b * NSEQ + token) * DMODEL + h * DHEAD + et * 16 + col] =
            f2b(o[mt][et][r] * inv);
    }
}

// ---------------- Stage 3: output projection + bias (r0-proven: 128^2, BK=32, dbuf) ----------------
__global__ __launch_bounds__(256, 4) void out_gemm(
    const u16* __restrict__ attn, const u16* __restrict__ Wo,
    const float* __restrict__ bo, float* __restrict__ out)
{
  __shared__ __align__(16) u16 lA[2][128 * 32];
  __shared__ __align__(16) u16 lB[2][128 * 32];

  const int tid  = threadIdx.x;
  const int lane = tid & 63;
  const int w    = tid >> 6;
  const int wm   = w >> 1, wn = w & 1;
  const int col  = lane & 15;
  const int quad = lane >> 4;
  const int bm = blockIdx.x;   // 0..63
  const int bn = blockIdx.y;   // 0..5

  const int m0 = bm * 128;
  const int n0 = bn * 128;

  const int srow = lane >> 2;
  const int sg   = (lane & 3) ^ ((srow >> 1) & 3);
  const u16* gA0 = attn + (size_t)(m0 + w * 32 + srow) * DMODEL + sg * 8;
  const u16* gB0 = Wo   + (size_t)(n0 + w * 32 + srow) * DMODEL + sg * 8;

  f4 acc[4][4];
#pragma unroll
  for (int i = 0; i < 4; i++)
#pragma unroll
    for (int jj = 0; jj < 4; jj++) acc[i][jj] = (f4)0.0f;

  gl_lds16(gA0, &lA[0][(w * 32) * 32]);
  gl_lds16(gA0 + (size_t)16 * DMODEL, &lA[0][(w * 32 + 16) * 32]);
  gl_lds16(gB0, &lB[0][(w * 32) * 32]);
  gl_lds16(gB0 + (size_t)16 * DMODEL, &lB[0][(w * 32 + 16) * 32]);

  for (int it = 0; it < 24; it++) {
    const int cur = it & 1;
    __syncthreads();
    if (it < 23) {
      const int kk = (it + 1) * 32;
      gl_lds16(gA0 + kk, &lA[cur ^ 1][(w * 32) * 32]);
      gl_lds16(gA0 + (size_t)16 * DMODEL + kk, &lA[cur ^ 1][(w * 32 + 16) * 32]);
      gl_lds16(gB0 + kk, &lB[cur ^ 1][(w * 32) * 32]);
      gl_lds16(gB0 + (size_t)16 * DMODEL + kk, &lB[cur ^ 1][(w * 32 + 16) * 32]);
    }

    bf8 af[4], bfr[4];
#pragma unroll
    for (int mt = 0; mt < 4; mt++) {
      const int row = wm * 64 + mt * 16 + col;
      af[mt] = *(const bf8*)&lA[cur][row * 32 + ((quad ^ ((row >> 1) & 3)) << 3)];
    }
#pragma unroll
    for (int nt = 0; nt < 4; nt++) {
      const int row = wn * 64 + nt * 16 + col;
      bfr[nt] = *(const bf8*)&lB[cur][row * 32 + ((quad ^ ((row >> 1) & 3)) << 3)];
    }
#pragma unroll
    for (int mt = 0; mt < 4; mt++)
#pragma unroll
      for (int nt = 0; nt < 4; nt++)
        acc[mt][nt] = __builtin_amdgcn_mfma_f32_16x16x32_bf16(af[mt], bfr[nt], acc[mt][nt], 0, 0, 0);
  }

  const int mw0 = m0 + wm * 64, nw0 = n0 + wn * 64;
#pragma unroll
  for (int mt = 0; mt < 4; mt++)
#pragma unroll
    for (int nt = 0; nt < 4; nt++) {
      const int n = nw0 + nt * 16 + col;
      const float bias = bo[n];
#pragma unroll
      for (int r = 0; r < 4; r++) {
        const int row = mw0 + mt * 16 + quad * 4 + r;
        out[(size_t)row * DMODEL + n] = acc[mt][nt][r] + bias;
      }
    }
}

extern "C" void kernel_launch(void* const* d_in, const int* in_sizes, int n_in,
                              void* d_out, int out_size, void* d_ws, size_t ws_size,
                              hipStream_t stream) {
  const float* x  = (const float*)d_in[0];
  const float* Wq = (const float*)d_in[1];
  const float* Wk = (const float*)d_in[2];
  const float* Wv = (const float*)d_in[3];
  const float* Wo = (const float*)d_in[4];
  const float* bo = (const float*)d_in[5];
  float* out = (float*)d_out;

  u16* xb   = (u16*)d_ws;
  u16* wqb  = xb  + XELEMS;
  u16* wkb  = wqb + WELEMS;
  u16* wvb  = wkb + WELEMS;
  u16* wob  = wvb + WELEMS;
  u16* q    = wob + WELEMS;
  u16* k    = q   + XELEMS;
  u16* vt   = k   + XELEMS;
  u16* attn = vt  + XELEMS;

  CvtArgs ca;
  ca.src[0] = x;  ca.src[1] = Wq;  ca.src[2] = Wk;  ca.src[3] = Wv;  ca.src[4] = Wo;
  ca.dst[0] = xb; ca.dst[1] = wqb; ca.dst[2] = wkb; ca.dst[3] = wvb; ca.dst[4] = wob;

  cvt_kernel<<<dim3((GTOT + 255) / 256), 256, 0, stream>>>(ca);
  qkv_gemm<<<dim3(576), 512, 0, stream>>>(xb, wqb, wkb, wvb, q, k, vt);
  attn_kernel<<<dim3(768), 256, 0, stream>>>(q, k, vt, attn);
  out_gemm<<<dim3(64, 6), 256, 0, stream>>>(attn, wob, bo, out);
}

// Round 9
// 211.563 us; speedup vs baseline: 1.1785x; 1.1785x over previous
//
#include <hip/hip_runtime.h>
#include <hip/hip_bf16.h>

// Problem: B=8, N=1024, D=768, H=12, dh=64. I/O FP32; internal compute bf16 MFMA.
// Pipeline: [0] cvt x,Wq,Wk,Wv,Wo fp32->bf16 into ws
//           [1] QKV gemm: BM=256 BN=128 BK=64, 8 waves, TRI-buffered LDS,
//               counted vmcnt(6) + raw s_barrier, L2-blocked XCD swizzle
//               (round-6 proven 48.5 us) -> q,k [B,H,N,64], vt [B,H,64,N]
//           [2] flash attention: XCD-local grid, KV-tile=64, SINGLE-buffered K/V
//               with REGISTER prefetch (T14: issue t+1 global loads before compute
//               of t; barrier; ds_write; barrier). LDS 34.4 KB -> 4 blocks/CU
//               (16 waves/CU). SWAPPED QK^T (mfma(K,Q) -> S^T, kv lane-local),
//               packed P via f2b + ds_write_b64 into [32][72] wave-private buffer;
//               PV A-frag is one conflict-free ds_read_b128. ones-MFMA row-sums.
//           [3] out gemm: r0-proven 128^2 BK=32 dbuf structure + bias (fp32 out).
// MFMA 16x16x32 bf16. A/B frag: elem(lane&15, k=quad*8+j). C/D: col=lane&15, row=quad*4+r.
// 128B-row LDS swizzle (qkv/attn): granule g of row r stored at g^(r&7).
// 64B-row (BK=32) swizzle (out): granule g of row r at g^((r>>1)&3).

typedef unsigned short u16;
typedef unsigned int u32;
typedef __attribute__((ext_vector_type(8))) short bf8;   // 8 bf16 in 4 VGPRs
typedef __attribute__((ext_vector_type(4))) short bf4;   // 4 bf16 in 2 VGPRs
typedef __attribute__((ext_vector_type(4))) float f4;
typedef __attribute__((ext_vector_type(4))) unsigned short us4;

#define NB 8
#define NSEQ 1024
#define DMODEL 768
#define NHEAD 12
#define DHEAD 64

#define XELEMS   (NB * NSEQ * DMODEL)          // 6291456
#define WELEMS   (DMODEL * DMODEL)             // 589824

__device__ __forceinline__ float b2f(u16 u) {
  union { unsigned int i; float f; } c; c.i = ((unsigned int)u) << 16; return c.f;
}
__device__ __forceinline__ u16 f2b(float f) {
  union { float f; unsigned int i; } c; c.f = f;
  unsigned int r = c.i + 0x7fffu + ((c.i >> 16) & 1u);
  return (u16)(r >> 16);
}
__device__ __forceinline__ void gl_lds16(const u16* g, u16* l) {
  __builtin_amdgcn_global_load_lds(
      (const __attribute__((address_space(1))) unsigned int*)g,
      (__attribute__((address_space(3))) unsigned int*)l, 16, 0, 0);
}

// ---------------- Stage 0: fp32 -> bf16 conversion ----------------
struct CvtArgs {
  const float* src[5];
  u16* dst[5];
};
#define G0 (XELEMS / 4)
#define GW (WELEMS / 4)
#define GTOT (G0 + 4 * GW)

__global__ __launch_bounds__(256) void cvt_kernel(CvtArgs a) {
  size_t g = (size_t)blockIdx.x * 256 + threadIdx.x;
  if (g >= GTOT) return;
  int t; size_t off;
  if (g < G0) { t = 0; off = g; }
  else { size_t r = g - G0; t = 1 + (int)(r / GW); off = r % GW; }
  f4 v = *(const f4*)(a.src[t] + off * 4);
  us4 o;
  o[0] = f2b(v[0]); o[1] = f2b(v[1]); o[2] = f2b(v[2]); o[3] = f2b(v[3]);
  *(us4*)(a.dst[t] + off * 4) = o;
}

// ---------------- Stage 1: QKV projection (BM=256, BN=128, BK=64, tri-buf, counted vmcnt) ----------------
// Round-6 proven version (48.5 us). L2-blocked XCD swizzle.
__global__ __launch_bounds__(512, 2) void qkv_gemm(
    const u16* __restrict__ x, const u16* __restrict__ Wq,
    const u16* __restrict__ Wk, const u16* __restrict__ Wv,
    u16* __restrict__ q, u16* __restrict__ k, u16* __restrict__ vt)
{
  __shared__ __align__(16) u16 lA[3][256 * 64];   // 32 KB x3
  __shared__ __align__(16) u16 lB[3][128 * 64];   // 16 KB x3   total 144 KB

  const int tid  = threadIdx.x;
  const int lane = tid & 63;
  const int w    = tid >> 6;        // 0..7
  const int wm4  = w >> 1;          // 0..3
  const int wn2  = w & 1;           // 0..1
  const int col  = lane & 15;
  const int quad = lane >> 4;

  // L2-blocked XCD swizzle: bid -> (xcd, j); j = bng*24 + bm4*6 + bn6
  const int bid = blockIdx.x;
  const int xcd = bid & 7;
  const int j   = bid >> 3;         // 0..71
  const int bng = j / 24;           // 0..2
  const int bm4 = (j % 24) / 6;     // 0..3
  const int bn6 = j % 6;            // 0..5
  const int bm  = xcd * 4 + bm4;    // 0..31
  const int bn  = bng * 6 + bn6;    // 0..17

  const int m0 = bm * 256;
  const int proj = bn / 6;                      // 0=q,1=k,2=v
  const u16* Wsel = (proj == 0) ? Wq : (proj == 1 ? Wk : Wv);
  const int nrem0 = (bn % 6) * 128;

  const int srow8 = lane >> 3;                  // 0..7
  const int sg    = (lane & 7) ^ srow8;         // pre-swizzled source granule

  const u16* gA = x    + (size_t)(m0    + w * 8 + srow8) * DMODEL + sg * 8;
  const u16* gB = Wsel + (size_t)(nrem0 + w * 8 + srow8) * DMODEL + sg * 8;

  f4 acc[4][4];
#pragma unroll
  for (int i = 0; i < 4; i++)
#pragma unroll
    for (int jj = 0; jj < 4; jj++) acc[i][jj] = (f4)0.0f;

#define QKV_STAGE(T, BUF)                                                      \
  do {                                                                         \
    const int kk_ = (T) * 64;                                                  \
    _Pragma("unroll")                                                          \
    for (int r_ = 0; r_ < 4; r_++)                                             \
      gl_lds16(gA + (size_t)r_ * 64 * DMODEL + kk_,                            \
               &lA[BUF][(r_ * 64 + w * 8) * 64]);                              \
    _Pragma("unroll")                                                          \
    for (int r_ = 0; r_ < 2; r_++)                                             \
      gl_lds16(gB + (size_t)r_ * 64 * DMODEL + kk_,                            \
               &lB[BUF][(r_ * 64 + w * 8) * 64]);                              \
  } while (0)

  QKV_STAGE(0, 0);
  QKV_STAGE(1, 1);

  for (int t = 0; t < 12; t++) {
    if (t < 11) { asm volatile("s_waitcnt vmcnt(6)" ::: "memory"); }
    else        { asm volatile("s_waitcnt vmcnt(0)" ::: "memory"); }
    __builtin_amdgcn_s_barrier();
    asm volatile("" ::: "memory");

    if (t < 10) QKV_STAGE(t + 2, (t + 2) % 3);

    const int buf = t % 3;
    bf8 af[4][2], bfr[4][2];
#pragma unroll
    for (int mt = 0; mt < 4; mt++) {
      const int row = wm4 * 64 + mt * 16 + col;
#pragma unroll
      for (int kt = 0; kt < 2; kt++)
        af[mt][kt] = *(const bf8*)&lA[buf][row * 64 + (((kt * 4 + quad) ^ (row & 7)) << 3)];
    }
#pragma unroll
    for (int nt = 0; nt < 4; nt++) {
      const int row = wn2 * 64 + nt * 16 + col;
#pragma unroll
      for (int kt = 0; kt < 2; kt++)
        bfr[nt][kt] = *(const bf8*)&lB[buf][row * 64 + (((kt * 4 + quad) ^ (row & 7)) << 3)];
    }

    __builtin_amdgcn_s_setprio(1);
#pragma unroll
    for (int mt = 0; mt < 4; mt++)
#pragma unroll
      for (int nt = 0; nt < 4; nt++)
#pragma unroll
        for (int kt = 0; kt < 2; kt++)
          acc[mt][nt] = __builtin_amdgcn_mfma_f32_16x16x32_bf16(af[mt][kt], bfr[nt][kt], acc[mt][nt], 0, 0, 0);
    __builtin_amdgcn_s_setprio(0);
  }
#undef QKV_STAGE

  const int mw0 = m0 + wm4 * 64, nw0 = nrem0 + wn2 * 64;
  if (proj == 2) {
#pragma unroll
    for (int mt = 0; mt < 4; mt++) {
#pragma unroll
      for (int nt = 0; nt < 4; nt++) {
        const int nc = nw0 + nt * 16 + col;
        const int h = nc >> 6, e = nc & 63;
        const int t0 = mw0 + mt * 16 + quad * 4;
        const int b = t0 >> 10, tok0 = t0 & 1023;
        us4 pk;
#pragma unroll
        for (int r = 0; r < 4; r++) pk[r] = f2b(acc[mt][nt][r]);
        *(us4*)(vt + ((size_t)(b * NHEAD + h) * DHEAD + e) * NSEQ + tok0) = pk;
      }
    }
  } else {
    u16* dst = (proj == 0) ? q : k;
#pragma unroll
    for (int mt = 0; mt < 4; mt++) {
#pragma unroll
      for (int nt = 0; nt < 4; nt++) {
        const int nc = nw0 + nt * 16 + col;
        const int h = nc >> 6, e = nc & 63;
#pragma unroll
        for (int r = 0; r < 4; r++) {
          const int t = mw0 + mt * 16 + quad * 4 + r;
          const int b = t >> 10, tok = t & 1023;
          dst[((size_t)(b * NHEAD + h) * NSEQ + tok) * DHEAD + e] = f2b(acc[mt][nt][r]);
        }
      }
    }
  }
}

// ---------------- Stage 2: flash attention (single-buf K/V + register prefetch, T14) ----------------
// 1D grid 768: idx = qc*96 + bh  ->  idx%8 == bh%8, all q-chunks of one (b,h) on one XCD.
// Per tile: issue t+1 reg-loads BEFORE compute of t (HBM/L2 latency hides under
// QK+P+PV); after compute: barrier (readers done) -> ds_write t+1 -> barrier.
// LDS 34.4 KB -> 4 blocks/CU. Same bytes/swizzle as the gl_lds16 version: load from
// pre-swizzled global addr into reg, write to the linear LDS slot.
// S^T = mfma(K, Q): lane holds (q = col, kv = kvt*16 + quad*4 + r); pack 4 bf16 via
// f2b, ONE ds_write_b64 at ldsP[w][q][kv]; PV A-frag = one ds_read_b128.
__global__ __launch_bounds__(256, 4) void attn_kernel(
    const u16* __restrict__ q, const u16* __restrict__ k,
    const u16* __restrict__ vt, u16* __restrict__ attn)
{
  __shared__ __align__(16) u16 ldsK[64 * 64];     // K tile [64 kv][64 e], swizzled, 8 KB
  __shared__ __align__(16) u16 ldsV[64 * 64];     // V^T tile [64 e][64 kv], swizzled, 8 KB
  __shared__ __align__(16) u16 ldsP[4][32][72];   // wave-private P [q-row][kv] (18.4 KB)

  const int tid  = threadIdx.x;
  const int lane = tid & 63;
  const int w    = tid >> 6;
  const int col  = lane & 15;
  const int quad = lane >> 4;

  const int idx = blockIdx.x;
  const int bh = idx % 96, qc = idx / 96;
  const int b = bh / 12, h = bh % 12;

  const size_t head = ((size_t)b * NHEAD + h) * NSEQ * DHEAD;  // works for q,k and vt
  const int q0 = qc * 128 + w * 32;

  const int srow8 = lane >> 3;                // 0..7 row within an 8-row chunk
  const int lg    = lane & 7;                 // granule slot in LDS (linear)
  const int sg    = lg ^ srow8;               // pre-swizzled source granule

  // per-thread staging pointers: chunks i=0,1 -> rows (w*2+i)*8 + srow8
  const int li0 = w * 2, li1 = w * 2 + 1;
  const u16* ksrc0 = k  + head + (size_t)(li0 * 8 + srow8) * DHEAD + sg * 8;
  const u16* ksrc1 = k  + head + (size_t)(li1 * 8 + srow8) * DHEAD + sg * 8;
  const u16* vsrc0 = vt + head + (size_t)(li0 * 8 + srow8) * NSEQ + sg * 8;
  const u16* vsrc1 = vt + head + (size_t)(li1 * 8 + srow8) * NSEQ + sg * 8;
  u16* kdst0 = &ldsK[(li0 * 8 + srow8) * 64 + lg * 8];
  u16* kdst1 = &ldsK[(li1 * 8 + srow8) * 64 + lg * 8];
  u16* vdst0 = &ldsV[(li0 * 8 + srow8) * 64 + lg * 8];
  u16* vdst1 = &ldsV[(li1 * 8 + srow8) * 64 + lg * 8];

  // ones B-frag for l row-sums via MFMA
  bf8 onesf;
#pragma unroll
  for (int jj = 0; jj < 8; jj++) onesf[jj] = (short)0x3F80;  // bf16 1.0

  // Q fragments, pre-scaled by 1/sqrt(64)=0.125 (exact in bf16)
  bf8 qf[2][2];
#pragma unroll
  for (int qt = 0; qt < 2; qt++)
#pragma unroll
    for (int kt = 0; kt < 2; kt++) {
      const int row = q0 + qt * 16 + col;
      bf8 t = *(const bf8*)(q + head + (size_t)row * DHEAD + kt * 32 + quad * 8);
#pragma unroll
      for (int jj = 0; jj < 8; jj++) t[jj] = (short)f2b(b2f((u16)t[jj]) * 0.125f);
      qf[qt][kt] = t;
    }

  f4 lacc[2];
  f4 o[2][4];
#pragma unroll
  for (int mt = 0; mt < 2; mt++) {
    lacc[mt] = (f4)0.0f;
#pragma unroll
    for (int et = 0; et < 4; et++) o[mt][et] = (f4)0.0f;
  }

  // prologue: tile 0 -> regs -> LDS
  {
    bf8 k0 = *(const bf8*)ksrc0;
    bf8 k1 = *(const bf8*)ksrc1;
    bf8 v0 = *(const bf8*)vsrc0;
    bf8 v1 = *(const bf8*)vsrc1;
    *(bf8*)kdst0 = k0; *(bf8*)kdst1 = k1;
    *(bf8*)vdst0 = v0; *(bf8*)vdst1 = v1;
  }
  __syncthreads();

  for (int t = 0; t < NSEQ / 64; t++) {
    // T14: issue next tile's global loads BEFORE compute (latency hides under it)
    bf8 nk0, nk1, nv0, nv1;
    if (t < NSEQ / 64 - 1) {
      const int kb2 = (t + 1) * 64;
      nk0 = *(const bf8*)(ksrc0 + (size_t)kb2 * DHEAD);
      nk1 = *(const bf8*)(ksrc1 + (size_t)kb2 * DHEAD);
      nv0 = *(const bf8*)(vsrc0 + kb2);
      nv1 = *(const bf8*)(vsrc1 + kb2);
    }

    // S^T = K @ (Q/8)^T  [64 kv x 32 q] per wave; lane: q = col, kv = kvt*16+quad*4+r
    f4 st[4][2];
#pragma unroll
    for (int kvt = 0; kvt < 4; kvt++)
#pragma unroll
      for (int qt = 0; qt < 2; qt++) st[kvt][qt] = (f4)0.0f;
#pragma unroll
    for (int kt = 0; kt < 2; kt++) {
      bf8 kf[4];
#pragma unroll
      for (int kvt = 0; kvt < 4; kvt++) {
        const int row = kvt * 16 + col;
        kf[kvt] = *(const bf8*)&ldsK[row * 64 + (((kt * 4 + quad) ^ (col & 7)) << 3)];
      }
      __builtin_amdgcn_s_setprio(1);
#pragma unroll
      for (int kvt = 0; kvt < 4; kvt++)
#pragma unroll
        for (int qt = 0; qt < 2; qt++)
          st[kvt][qt] = __builtin_amdgcn_mfma_f32_16x16x32_bf16(kf[kvt], qf[qt][kt], st[kvt][qt], 0, 0, 0);
      __builtin_amdgcn_s_setprio(0);
    }

    // P = exp(S): f2b (proven bit-ops RNE) packed in-register, ONE ds_write_b64 per acc
#pragma unroll
    for (int kvt = 0; kvt < 4; kvt++)
#pragma unroll
      for (int qt = 0; qt < 2; qt++) {
        const f4 p = st[kvt][qt];
        bf4 pw;
        pw[0] = (short)f2b(__expf(p[0]));
        pw[1] = (short)f2b(__expf(p[1]));
        pw[2] = (short)f2b(__expf(p[2]));
        pw[3] = (short)f2b(__expf(p[3]));
        *(bf4*)&ldsP[w][qt * 16 + col][kvt * 16 + quad * 4] = pw;
      }
    asm volatile("" ::: "memory");   // order P writes before PV reads (aliasing guard)

    // PV: vf hoisted (shared by both mt); pf = one conflict-free ds_read_b128
#pragma unroll
    for (int kt2 = 0; kt2 < 2; kt2++) {
      bf8 vf[4];
#pragma unroll
      for (int et = 0; et < 4; et++) {
        const int row = et * 16 + col;
        vf[et] = *(const bf8*)&ldsV[row * 64 + (((kt2 * 4 + quad) ^ (col & 7)) << 3)];
      }
#pragma unroll
      for (int mt = 0; mt < 2; mt++) {
        const bf8 pf = *(const bf8*)&ldsP[w][mt * 16 + col][kt2 * 32 + quad * 8];
        __builtin_amdgcn_s_setprio(1);
        lacc[mt] = __builtin_amdgcn_mfma_f32_16x16x32_bf16(pf, onesf, lacc[mt], 0, 0, 0);
#pragma unroll
        for (int et = 0; et < 4; et++)
          o[mt][et] = __builtin_amdgcn_mfma_f32_16x16x32_bf16(pf, vf[et], o[mt][et], 0, 0, 0);
        __builtin_amdgcn_s_setprio(0);
      }
    }

    // stage t+1 into LDS: wait all readers of tile t, write, publish
    if (t < NSEQ / 64 - 1) {
      __syncthreads();
      *(bf8*)kdst0 = nk0; *(bf8*)kdst1 = nk1;
      *(bf8*)vdst0 = nv0; *(bf8*)vdst1 = nv1;
      __syncthreads();
    }
  }

  // epilogue: every lane already holds its row-sum in lacc (all n-cols equal)
#pragma unroll
  for (int mt = 0; mt < 2; mt++)
#pragma unroll
    for (int r = 0; r < 4; r++) {
      const float inv = 1.0f / lacc[mt][r];
      const int token = q0 + mt * 16 + quad * 4 + r;
#pragma unroll
      for (int et = 0; et < 4; et++)
        attn[(size_t)(b * NSEQ + token) * DMODEL + h * DHEAD + et * 16 + col] =
            f2b(o[mt][et][r] * inv);
    }
}

// ---------------- Stage 3: output projection + bias (r0-proven: 128^2, BK=32, dbuf) ----------------
__global__ __launch_bounds__(256, 4) void out_gemm(
    const u16* __restrict__ attn, const u16* __restrict__ Wo,
    const float* __restrict__ bo, float* __restrict__ out)
{
  __shared__ __align__(16) u16 lA[2][128 * 32];
  __shared__ __align__(16) u16 lB[2][128 * 32];

  const int tid  = threadIdx.x;
  const int lane = tid & 63;
  const int w    = tid >> 6;
  const int wm   = w >> 1, wn = w & 1;
  const int col  = lane & 15;
  const int quad = lane >> 4;
  const int bm = blockIdx.x;   // 0..63
  const int bn = blockIdx.y;   // 0..5

  const int m0 = bm * 128;
  const int n0 = bn * 128;

  const int srow = lane >> 2;
  const int sg   = (lane & 3) ^ ((srow >> 1) & 3);
  const u16* gA0 = attn + (size_t)(m0 + w * 32 + srow) * DMODEL + sg * 8;
  const u16* gB0 = Wo   + (size_t)(n0 + w * 32 + srow) * DMODEL + sg * 8;

  f4 acc[4][4];
#pragma unroll
  for (int i = 0; i < 4; i++)
#pragma unroll
    for (int jj = 0; jj < 4; jj++) acc[i][jj] = (f4)0.0f;

  gl_lds16(gA0, &lA[0][(w * 32) * 32]);
  gl_lds16(gA0 + (size_t)16 * DMODEL, &lA[0][(w * 32 + 16) * 32]);
  gl_lds16(gB0, &lB[0][(w * 32) * 32]);
  gl_lds16(gB0 + (size_t)16 * DMODEL, &lB[0][(w * 32 + 16) * 32]);

  for (int it = 0; it < 24; it++) {
    const int cur = it & 1;
    __syncthreads();
    if (it < 23) {
      const int kk = (it + 1) * 32;
      gl_lds16(gA0 + kk, &lA[cur ^ 1][(w * 32) * 32]);
      gl_lds16(gA0 + (size_t)16 * DMODEL + kk, &lA[cur ^ 1][(w * 32 + 16) * 32]);
      gl_lds16(gB0 + kk, &lB[cur ^ 1][(w * 32) * 32]);
      gl_lds16(gB0 + (size_t)16 * DMODEL + kk, &lB[cur ^ 1][(w * 32 + 16) * 32]);
    }

    bf8 af[4], bfr[4];
#pragma unroll
    for (int mt = 0; mt < 4; mt++) {
      const int row = wm * 64 + mt * 16 + col;
      af[mt] = *(const bf8*)&lA[cur][row * 32 + ((quad ^ ((row >> 1) & 3)) << 3)];
    }
#pragma unroll
    for (int nt = 0; nt < 4; nt++) {
      const int row = wn * 64 + nt * 16 + col;
      bfr[nt] = *(const bf8*)&lB[cur][row * 32 + ((quad ^ ((row >> 1) & 3)) << 3)];
    }
#pragma unroll
    for (int mt = 0; mt < 4; mt++)
#pragma unroll
      for (int nt = 0; nt < 4; nt++)
        acc[mt][nt] = __builtin_amdgcn_mfma_f32_16x16x32_bf16(af[mt], bfr[nt], acc[mt][nt], 0, 0, 0);
  }

  const int mw0 = m0 + wm * 64, nw0 = n0 + wn * 64;
#pragma unroll
  for (int mt = 0; mt < 4; mt++)
#pragma unroll
    for (int nt = 0; nt < 4; nt++) {
      const int n = nw0 + nt * 16 + col;
      const float bias = bo[n];
#pragma unroll
      for (int r = 0; r < 4; r++) {
        const int row = mw0 + mt * 16 + quad * 4 + r;
        out[(size_t)row * DMODEL + n] = acc[mt][nt][r] + bias;
      }
    }
}

extern "C" void kernel_launch(void* const* d_in, const int* in_sizes, int n_in,
                              void* d_out, int out_size, void* d_ws, size_t ws_size,
                              hipStream_t stream) {
  const float* x  = (const float*)d_in[0];
  const float* Wq = (const float*)d_in[1];
  const float* Wk = (const float*)d_in[2];
  const float* Wv = (const float*)d_in[3];
  const float* Wo = (const float*)d_in[4];
  const float* bo = (const float*)d_in[5];
  float* out = (float*)d_out;

  u16* xb   = (u16*)d_ws;
  u16* wqb  = xb  + XELEMS;
  u16* wkb  = wqb + WELEMS;
  u16* wvb  = wkb + WELEMS;
  u16* wob  = wvb + WELEMS;
  u16* q    = wob + WELEMS;
  u16* k    = q   + XELEMS;
  u16* vt   = k   + XELEMS;
  u16* attn = vt  + XELEMS;

  CvtArgs ca;
  ca.src[0] = x;  ca.src[1] = Wq;  ca.src[2] = Wk;  ca.src[3] = Wv;  ca.src[4] = Wo;
  ca.dst[0] = xb; ca.dst[1] = wqb; ca.dst[2] = wkb; ca.dst[3] = wvb; ca.dst[4] = wob;

  cvt_kernel<<<dim3((GTOT + 255) / 256), 256, 0, stream>>>(ca);
  qkv_gemm<<<dim3(576), 512, 0, stream>>>(xb, wqb, wkb, wvb, q, k, vt);
  attn_kernel<<<dim3(768), 256, 0, stream>>>(q, k, vt, attn);
  out_gemm<<<dim3(64, 6), 256, 0, stream>>>(attn, wob, bo, out);
}

// Round 10
// 195.961 us; speedup vs baseline: 1.2723x; 1.0796x over previous
//
#include <hip/hip_runtime.h>
#include <hip/hip_bf16.h>

// Problem: B=8, N=1024, D=768, H=12, dh=64. I/O FP32; internal compute bf16 MFMA.
// Pipeline: [0] cvt x,Wq,Wk,Wv,Wo fp32->bf16 into ws
//           [1] QKV gemm: BM=256 BN=128 BK=64, 8 waves, TRI-buffered LDS,
//               counted vmcnt(6) + raw s_barrier, L2-blocked XCD swizzle
//               (round-6 proven 48.5 us) -> q,k [B,H,N,64], vt [B,H,64,N]
//           [2] flash attention: XCD-local grid, KV-tile=64, dbuf K/V staging via
//               global_load_lds (wave-linear LDS writes: conflict-free), SWAPPED
//               QK^T (mfma(K,Q) -> S^T, kv lane-local), packed P via f2b +
//               ds_write_b64 into [32][72] wave-private buffer; PV A-frag is one
//               conflict-free ds_read_b128. ones-MFMA row-sums.
//           [3] out gemm: r0-proven 128^2 BK=32 dbuf structure + bias (fp32 out).
// MFMA 16x16x32 bf16. A/B frag: elem(lane&15, k=quad*8+j). C/D: col=lane&15, row=quad*4+r.
// 128B-row LDS swizzle (qkv/attn): granule g of row r stored at g^(r&7).
// 64B-row (BK=32) swizzle (out): granule g of row r at g^((r>>1)&3).

typedef unsigned short u16;
typedef unsigned int u32;
typedef __attribute__((ext_vector_type(8))) short bf8;   // 8 bf16 in 4 VGPRs
typedef __attribute__((ext_vector_type(4))) short bf4;   // 4 bf16 in 2 VGPRs
typedef __attribute__((ext_vector_type(4))) float f4;
typedef __attribute__((ext_vector_type(4))) unsigned short us4;

#define NB 8
#define NSEQ 1024
#define DMODEL 768
#define NHEAD 12
#define DHEAD 64

#define XELEMS   (NB * NSEQ * DMODEL)          // 6291456
#define WELEMS   (DMODEL * DMODEL)             // 589824

__device__ __forceinline__ float b2f(u16 u) {
  union { unsigned int i; float f; } c; c.i = ((unsigned int)u) << 16; return c.f;
}
__device__ __forceinline__ u16 f2b(float f) {
  union { float f; unsigned int i; } c; c.f = f;
  unsigned int r = c.i + 0x7fffu + ((c.i >> 16) & 1u);
  return (u16)(r >> 16);
}
__device__ __forceinline__ void gl_lds16(const u16* g, u16* l) {
  __builtin_amdgcn_global_load_lds(
      (const __attribute__((address_space(1))) unsigned int*)g,
      (__attribute__((address_space(3))) unsigned int*)l, 16, 0, 0);
}

// ---------------- Stage 0: fp32 -> bf16 conversion ----------------
struct CvtArgs {
  const float* src[5];
  u16* dst[5];
};
#define G0 (XELEMS / 4)
#define GW (WELEMS / 4)
#define GTOT (G0 + 4 * GW)

__global__ __launch_bounds__(256) void cvt_kernel(CvtArgs a) {
  size_t g = (size_t)blockIdx.x * 256 + threadIdx.x;
  if (g >= GTOT) return;
  int t; size_t off;
  if (g < G0) { t = 0; off = g; }
  else { size_t r = g - G0; t = 1 + (int)(r / GW); off = r % GW; }
  f4 v = *(const f4*)(a.src[t] + off * 4);
  us4 o;
  o[0] = f2b(v[0]); o[1] = f2b(v[1]); o[2] = f2b(v[2]); o[3] = f2b(v[3]);
  *(us4*)(a.dst[t] + off * 4) = o;
}

// ---------------- Stage 1: QKV projection (BM=256, BN=128, BK=64, tri-buf, counted vmcnt) ----------------
// Round-6 proven version (48.5 us). L2-blocked XCD swizzle.
__global__ __launch_bounds__(512, 2) void qkv_gemm(
    const u16* __restrict__ x, const u16* __restrict__ Wq,
    const u16* __restrict__ Wk, const u16* __restrict__ Wv,
    u16* __restrict__ q, u16* __restrict__ k, u16* __restrict__ vt)
{
  __shared__ __align__(16) u16 lA[3][256 * 64];   // 32 KB x3
  __shared__ __align__(16) u16 lB[3][128 * 64];   // 16 KB x3   total 144 KB

  const int tid  = threadIdx.x;
  const int lane = tid & 63;
  const int w    = tid >> 6;        // 0..7
  const int wm4  = w >> 1;          // 0..3
  const int wn2  = w & 1;           // 0..1
  const int col  = lane & 15;
  const int quad = lane >> 4;

  // L2-blocked XCD swizzle: bid -> (xcd, j); j = bng*24 + bm4*6 + bn6
  const int bid = blockIdx.x;
  const int xcd = bid & 7;
  const int j   = bid >> 3;         // 0..71
  const int bng = j / 24;           // 0..2
  const int bm4 = (j % 24) / 6;     // 0..3
  const int bn6 = j % 6;            // 0..5
  const int bm  = xcd * 4 + bm4;    // 0..31
  const int bn  = bng * 6 + bn6;    // 0..17

  const int m0 = bm * 256;
  const int proj = bn / 6;                      // 0=q,1=k,2=v
  const u16* Wsel = (proj == 0) ? Wq : (proj == 1 ? Wk : Wv);
  const int nrem0 = (bn % 6) * 128;

  const int srow8 = lane >> 3;                  // 0..7
  const int sg    = (lane & 7) ^ srow8;         // pre-swizzled source granule

  const u16* gA = x    + (size_t)(m0    + w * 8 + srow8) * DMODEL + sg * 8;
  const u16* gB = Wsel + (size_t)(nrem0 + w * 8 + srow8) * DMODEL + sg * 8;

  f4 acc[4][4];
#pragma unroll
  for (int i = 0; i < 4; i++)
#pragma unroll
    for (int jj = 0; jj < 4; jj++) acc[i][jj] = (f4)0.0f;

#define QKV_STAGE(T, BUF)                                                      \
  do {                                                                         \
    const int kk_ = (T) * 64;                                                  \
    _Pragma("unroll")                                                          \
    for (int r_ = 0; r_ < 4; r_++)                                             \
      gl_lds16(gA + (size_t)r_ * 64 * DMODEL + kk_,                            \
               &lA[BUF][(r_ * 64 + w * 8) * 64]);                              \
    _Pragma("unroll")                                                          \
    for (int r_ = 0; r_ < 2; r_++)                                             \
      gl_lds16(gB + (size_t)r_ * 64 * DMODEL + kk_,                            \
               &lB[BUF][(r_ * 64 + w * 8) * 64]);                              \
  } while (0)

  QKV_STAGE(0, 0);
  QKV_STAGE(1, 1);

  for (int t = 0; t < 12; t++) {
    if (t < 11) { asm volatile("s_waitcnt vmcnt(6)" ::: "memory"); }
    else        { asm volatile("s_waitcnt vmcnt(0)" ::: "memory"); }
    __builtin_amdgcn_s_barrier();
    asm volatile("" ::: "memory");

    if (t < 10) QKV_STAGE(t + 2, (t + 2) % 3);

    const int buf = t % 3;
    bf8 af[4][2], bfr[4][2];
#pragma unroll
    for (int mt = 0; mt < 4; mt++) {
      const int row = wm4 * 64 + mt * 16 + col;
#pragma unroll
      for (int kt = 0; kt < 2; kt++)
        af[mt][kt] = *(const bf8*)&lA[buf][row * 64 + (((kt * 4 + quad) ^ (row & 7)) << 3)];
    }
#pragma unroll
    for (int nt = 0; nt < 4; nt++) {
      const int row = wn2 * 64 + nt * 16 + col;
#pragma unroll
      for (int kt = 0; kt < 2; kt++)
        bfr[nt][kt] = *(const bf8*)&lB[buf][row * 64 + (((kt * 4 + quad) ^ (row & 7)) << 3)];
    }

    __builtin_amdgcn_s_setprio(1);
#pragma unroll
    for (int mt = 0; mt < 4; mt++)
#pragma unroll
      for (int nt = 0; nt < 4; nt++)
#pragma unroll
        for (int kt = 0; kt < 2; kt++)
          acc[mt][nt] = __builtin_amdgcn_mfma_f32_16x16x32_bf16(af[mt][kt], bfr[nt][kt], acc[mt][nt], 0, 0, 0);
    __builtin_amdgcn_s_setprio(0);
  }
#undef QKV_STAGE

  const int mw0 = m0 + wm4 * 64, nw0 = nrem0 + wn2 * 64;
  if (proj == 2) {
#pragma unroll
    for (int mt = 0; mt < 4; mt++) {
#pragma unroll
      for (int nt = 0; nt < 4; nt++) {
        const int nc = nw0 + nt * 16 + col;
        const int h = nc >> 6, e = nc & 63;
        const int t0 = mw0 + mt * 16 + quad * 4;
        const int b = t0 >> 10, tok0 = t0 & 1023;
        us4 pk;
#pragma unroll
        for (int r = 0; r < 4; r++) pk[r] = f2b(acc[mt][nt][r]);
        *(us4*)(vt + ((size_t)(b * NHEAD + h) * DHEAD + e) * NSEQ + tok0) = pk;
      }
    }
  } else {
    u16* dst = (proj == 0) ? q : k;
#pragma unroll
    for (int mt = 0; mt < 4; mt++) {
#pragma unroll
      for (int nt = 0; nt < 4; nt++) {
        const int nc = nw0 + nt * 16 + col;
        const int h = nc >> 6, e = nc & 63;
#pragma unroll
        for (int r = 0; r < 4; r++) {
          const int t = mw0 + mt * 16 + quad * 4 + r;
          const int b = t >> 10, tok = t & 1023;
          dst[((size_t)(b * NHEAD + h) * NSEQ + tok) * DHEAD + e] = f2b(acc[mt][nt][r]);
        }
      }
    }
  }
}

// ---------------- Stage 2: flash attention (swapped QK^T, packed P, dbuf K/V) ----------------
// 1D grid 768: idx = qc*96 + bh  ->  idx%8 == bh%8, all q-chunks of one (b,h) on one XCD.
// S^T = mfma(K, Q): lane holds (q = col, kv = kvt*16 + quad*4 + r)  => kv runs are
// lane-local: pack 4 bf16 with f2b and store ONE ds_write_b64 at ldsP[w][q][kv].
// PV A-frag (m = q = lane&15, k = kv = quad*8+j) = single aligned ds_read_b128.
__global__ __launch_bounds__(256, 3) void attn_kernel(
    const u16* __restrict__ q, const u16* __restrict__ k,
    const u16* __restrict__ vt, u16* __restrict__ attn)
{
  __shared__ __align__(16) u16 ldsK[2][64 * 64];  // K tile [64 kv][64 e], swizzled, 8 KB x2
  __shared__ __align__(16) u16 ldsV[2][64 * 64];  // V^T tile [64 e][64 kv], swizzled, 8 KB x2
  __shared__ __align__(16) u16 ldsP[4][32][72];   // wave-private P [q-row][kv], stride-72 (18 KB)

  const int tid  = threadIdx.x;
  const int lane = tid & 63;
  const int w    = tid >> 6;
  const int col  = lane & 15;
  const int quad = lane >> 4;

  const int idx = blockIdx.x;
  const int bh = idx % 96, qc = idx / 96;
  const int b = bh / 12, h = bh % 12;

  const size_t head = ((size_t)b * NHEAD + h) * NSEQ * DHEAD;  // works for q,k and vt
  const int q0 = qc * 128 + w * 32;

  const int srow8 = lane >> 3;                // 0..7 row within an 8-row chunk
  const int sg    = (lane & 7) ^ srow8;       // swizzled source granule

  // ones B-frag for l row-sums via MFMA
  bf8 onesf;
#pragma unroll
  for (int jj = 0; jj < 8; jj++) onesf[jj] = (short)0x3F80;  // bf16 1.0

  // Q fragments, pre-scaled by 1/sqrt(64)=0.125 (exact in bf16)
  bf8 qf[2][2];
#pragma unroll
  for (int qt = 0; qt < 2; qt++)
#pragma unroll
    for (int kt = 0; kt < 2; kt++) {
      const int row = q0 + qt * 16 + col;
      bf8 t = *(const bf8*)(q + head + (size_t)row * DHEAD + kt * 32 + quad * 8);
#pragma unroll
      for (int jj = 0; jj < 8; jj++) t[jj] = (short)f2b(b2f((u16)t[jj]) * 0.125f);
      qf[qt][kt] = t;
    }

  f4 lacc[2];
  f4 o[2][4];
#pragma unroll
  for (int mt = 0; mt < 2; mt++) {
    lacc[mt] = (f4)0.0f;
#pragma unroll
    for (int et = 0; et < 4; et++) o[mt][et] = (f4)0.0f;
  }

  // prologue: stage tile 0 into buffer 0
#pragma unroll
  for (int i = 0; i < 2; i++) {
    const int li = w * 2 + i;
    gl_lds16(k  + head + (size_t)(li * 8 + srow8) * DHEAD + sg * 8, &ldsK[0][li * 512]);
    gl_lds16(vt + head + (size_t)(li * 8 + srow8) * NSEQ + sg * 8,  &ldsV[0][li * 512]);
  }

  for (int t = 0; t < NSEQ / 64; t++) {
    const int cur = t & 1;
    __syncthreads();   // drains tile-t loads; guards reuse of the other buffer
    if (t < NSEQ / 64 - 1) {
      const int kb2 = (t + 1) * 64;
#pragma unroll
      for (int i = 0; i < 2; i++) {
        const int li = w * 2 + i;
        gl_lds16(k  + head + (size_t)(kb2 + li * 8 + srow8) * DHEAD + sg * 8,
                 &ldsK[cur ^ 1][li * 512]);
        gl_lds16(vt + head + (size_t)(li * 8 + srow8) * NSEQ + kb2 + sg * 8,
                 &ldsV[cur ^ 1][li * 512]);
      }
    }

    // S^T = K @ (Q/8)^T  [64 kv x 32 q] per wave; lane: q = col, kv = kvt*16+quad*4+r
    f4 st[4][2];
#pragma unroll
    for (int kvt = 0; kvt < 4; kvt++)
#pragma unroll
      for (int qt = 0; qt < 2; qt++) st[kvt][qt] = (f4)0.0f;
#pragma unroll
    for (int kt = 0; kt < 2; kt++) {
      bf8 kf[4];
#pragma unroll
      for (int kvt = 0; kvt < 4; kvt++) {
        const int row = kvt * 16 + col;
        kf[kvt] = *(const bf8*)&ldsK[cur][row * 64 + (((kt * 4 + quad) ^ (col & 7)) << 3)];
      }
      __builtin_amdgcn_s_setprio(1);
#pragma unroll
      for (int kvt = 0; kvt < 4; kvt++)
#pragma unroll
        for (int qt = 0; qt < 2; qt++)
          st[kvt][qt] = __builtin_amdgcn_mfma_f32_16x16x32_bf16(kf[kvt], qf[qt][kt], st[kvt][qt], 0, 0, 0);
      __builtin_amdgcn_s_setprio(0);
    }

    // P = exp(S): f2b (proven bit-ops RNE) packed in-register, ONE ds_write_b64 per acc
#pragma unroll
    for (int kvt = 0; kvt < 4; kvt++)
#pragma unroll
      for (int qt = 0; qt < 2; qt++) {
        const f4 p = st[kvt][qt];
        bf4 pw;
        pw[0] = (short)f2b(__expf(p[0]));
        pw[1] = (short)f2b(__expf(p[1]));
        pw[2] = (short)f2b(__expf(p[2]));
        pw[3] = (short)f2b(__expf(p[3]));
        *(bf4*)&ldsP[w][qt * 16 + col][kvt * 16 + quad * 4] = pw;
      }
    asm volatile("" ::: "memory");   // order P writes before PV reads (aliasing guard)

    // PV: vf hoisted (shared by both mt); pf = one conflict-free ds_read_b128
#pragma unroll
    for (int kt2 = 0; kt2 < 2; kt2++) {
      bf8 vf[4];
#pragma unroll
      for (int et = 0; et < 4; et++) {
        const int row = et * 16 + col;
        vf[et] = *(const bf8*)&ldsV[cur][row * 64 + (((kt2 * 4 + quad) ^ (col & 7)) << 3)];
      }
#pragma unroll
      for (int mt = 0; mt < 2; mt++) {
        const bf8 pf = *(const bf8*)&ldsP[w][mt * 16 + col][kt2 * 32 + quad * 8];
        __builtin_amdgcn_s_setprio(1);
        lacc[mt] = __builtin_amdgcn_mfma_f32_16x16x32_bf16(pf, onesf, lacc[mt], 0, 0, 0);
#pragma unroll
        for (int et = 0; et < 4; et++)
          o[mt][et] = __builtin_amdgcn_mfma_f32_16x16x32_bf16(pf, vf[et], o[mt][et], 0, 0, 0);
        __builtin_amdgcn_s_setprio(0);
      }
    }
  }

  // epilogue: every lane already holds its row-sum in lacc (all n-cols equal)
#pragma unroll
  for (int mt = 0; mt < 2; mt++)
#pragma unroll
    for (int r = 0; r < 4; r++) {
      const float inv = 1.0f / lacc[mt][r];
      const int token = q0 + mt * 16 + quad * 4 + r;
#pragma unroll
      for (int et = 0; et < 4; et++)
        attn[(size_t)(b * NSEQ + token) * DMODEL + h * DHEAD + et * 16 + col] =
            f2b(o[mt][et][r] * inv);
    }
}

// ---------------- Stage 3: output projection + bias (r0-proven: 128^2, BK=32, dbuf) ----------------
__global__ __launch_bounds__(256, 4) void out_gemm(
    const u16* __restrict__ attn, const u16* __restrict__ Wo,
    const float* __restrict__ bo, float* __restrict__ out)
{
  __shared__ __align__(16) u16 lA[2][128 * 32];
  __shared__ __align__(16) u16 lB[2][128 * 32];

  const int tid  = threadIdx.x;
  const int lane = tid & 63;
  const int w    = tid >> 6;
  const int wm   = w >> 1, wn = w & 1;
  const int col  = lane & 15;
  const int quad = lane >> 4;
  const int bm = blockIdx.x;   // 0..63
  const int bn = blockIdx.y;   // 0..5

  const int m0 = bm * 128;
  const int n0 = bn * 128;

  const int srow = lane >> 2;
  const int sg   = (lane & 3) ^ ((srow >> 1) & 3);
  const u16* gA0 = attn + (size_t)(m0 + w * 32 + srow) * DMODEL + sg * 8;
  const u16* gB0 = Wo   + (size_t)(n0 + w * 32 + srow) * DMODEL + sg * 8;

  f4 acc[4][4];
#pragma unroll
  for (int i = 0; i < 4; i++)
#pragma unroll
    for (int jj = 0; jj < 4; jj++) acc[i][jj] = (f4)0.0f;

  gl_lds16(gA0, &lA[0][(w * 32) * 32]);
  gl_lds16(gA0 + (size_t)16 * DMODEL, &lA[0][(w * 32 + 16) * 32]);
  gl_lds16(gB0, &lB[0][(w * 32) * 32]);
  gl_lds16(gB0 + (size_t)16 * DMODEL, &lB[0][(w * 32 + 16) * 32]);

  for (int it = 0; it < 24; it++) {
    const int cur = it & 1;
    __syncthreads();
    if (it < 23) {
      const int kk = (it + 1) * 32;
      gl_lds16(gA0 + kk, &lA[cur ^ 1][(w * 32) * 32]);
      gl_lds16(gA0 + (size_t)16 * DMODEL + kk, &lA[cur ^ 1][(w * 32 + 16) * 32]);
      gl_lds16(gB0 + kk, &lB[cur ^ 1][(w * 32) * 32]);
      gl_lds16(gB0 + (size_t)16 * DMODEL + kk, &lB[cur ^ 1][(w * 32 + 16) * 32]);
    }

    bf8 af[4], bfr[4];
#pragma unroll
    for (int mt = 0; mt < 4; mt++) {
      const int row = wm * 64 + mt * 16 + col;
      af[mt] = *(const bf8*)&lA[cur][row * 32 + ((quad ^ ((row >> 1) & 3)) << 3)];
    }
#pragma unroll
    for (int nt = 0; nt < 4; nt++) {
      const int row = wn * 64 + nt * 16 + col;
      bfr[nt] = *(const bf8*)&lB[cur][row * 32 + ((quad ^ ((row >> 1) & 3)) << 3)];
    }
#pragma unroll
    for (int mt = 0; mt < 4; mt++)
#pragma unroll
      for (int nt = 0; nt < 4; nt++)
        acc[mt][nt] = __builtin_amdgcn_mfma_f32_16x16x32_bf16(af[mt], bfr[nt], acc[mt][nt], 0, 0, 0);
  }

  const int mw0 = m0 + wm * 64, nw0 = n0 + wn * 64;
#pragma unroll
  for (int mt = 0; mt < 4; mt++)
#pragma unroll
    for (int nt = 0; nt < 4; nt++) {
      const int n = nw0 + nt * 16 + col;
      const float bias = bo[n];
#pragma unroll
      for (int r = 0; r < 4; r++) {
        const int row = mw0 + mt * 16 + quad * 4 + r;
        out[(size_t)row * DMODEL + n] = acc[mt][nt][r] + bias;
      }
    }
}

extern "C" void kernel_launch(void* const* d_in, const int* in_sizes, int n_in,
                              void* d_out, int out_size, void* d_ws, size_t ws_size,
                              hipStream_t stream) {
  const float* x  = (const float*)d_in[0];
  const float* Wq = (const float*)d_in[1];
  const float* Wk = (const float*)d_in[2];
  const float* Wv = (const float*)d_in[3];
  const float* Wo = (const float*)d_in[4];
  const float* bo = (const float*)d_in[5];
  float* out = (float*)d_out;

  u16* xb   = (u16*)d_ws;
  u16* wqb  = xb  + XELEMS;
  u16* wkb  = wqb + WELEMS;
  u16* wvb  = wkb + WELEMS;
  u16* wob  = wvb + WELEMS;
  u16* q    = wob + WELEMS;
  u16* k    = q   + XELEMS;
  u16* vt   = k   + XELEMS;
  u16* attn = vt  + XELEMS;

  CvtArgs ca;
  ca.src[0] = x;  ca.src[1] = Wq;  ca.src[2] = Wk;  ca.src[3] = Wv;  ca.src[4] = Wo;
  ca.dst[0] = xb; ca.dst[1] = wqb; ca.dst[2] = wkb; ca.dst[3] = wvb; ca.dst[4] = wob;

  cvt_kernel<<<dim3((GTOT + 255) / 256), 256, 0, stream>>>(ca);
  qkv_gemm<<<dim3(576), 512, 0, stream>>>(xb, wqb, wkb, wvb, q, k, vt);
  attn_kernel<<<dim3(768), 256, 0, stream>>>(q, k, vt, attn);
  out_gemm<<<dim3(64, 6), 256, 0, stream>>>(attn, wob, bo, out);
}

// Round 11
// 185.806 us; speedup vs baseline: 1.3419x; 1.0547x over previous
//
#include <hip/hip_runtime.h>
#include <hip/hip_bf16.h>

// Problem: B=8, N=1024, D=768, H=12, dh=64. I/O FP32; internal compute bf16 MFMA.
// Pipeline: [0] cvt x,Wq,Wk,Wv,Wo fp32->bf16 into ws
//           [1] QKV gemm: BM=128 BN=128 BK=64, 4 waves, DOUBLE-buffered LDS (64 KB
//               -> 2 blocks/CU for barrier-stall coverage), r0-proven sync scheme
//               (stage t+1 before compute t; one __syncthreads/iter = vmcnt(0)+bar),
//               12 iters, 32-MFMA clusters, L2-blocked XCD swizzle over 1152 blocks.
//           [2] flash attention: XCD-local grid, KV-tile=64, dbuf K/V staging via
//               global_load_lds (wave-linear LDS writes: conflict-free), SWAPPED
//               QK^T (mfma(K,Q) -> S^T, kv lane-local), packed P via f2b +
//               ds_write_b64 into [32][72] wave-private buffer; PV A-frag is one
//               conflict-free ds_read_b128. ones-MFMA row-sums.
//           [3] out gemm: r0-proven 128^2 BK=32 dbuf structure + bias (fp32 out).
// MFMA 16x16x32 bf16. A/B frag: elem(lane&15, k=quad*8+j). C/D: col=lane&15, row=quad*4+r.
// 128B-row LDS swizzle (qkv/attn): granule g of row r stored at g^(r&7).
// 64B-row (BK=32) swizzle (out): granule g of row r at g^((r>>1)&3).

typedef unsigned short u16;
typedef unsigned int u32;
typedef __attribute__((ext_vector_type(8))) short bf8;   // 8 bf16 in 4 VGPRs
typedef __attribute__((ext_vector_type(4))) short bf4;   // 4 bf16 in 2 VGPRs
typedef __attribute__((ext_vector_type(4))) float f4;
typedef __attribute__((ext_vector_type(4))) unsigned short us4;

#define NB 8
#define NSEQ 1024
#define DMODEL 768
#define NHEAD 12
#define DHEAD 64

#define XELEMS   (NB * NSEQ * DMODEL)          // 6291456
#define WELEMS   (DMODEL * DMODEL)             // 589824

__device__ __forceinline__ float b2f(u16 u) {
  union { unsigned int i; float f; } c; c.i = ((unsigned int)u) << 16; return c.f;
}
__device__ __forceinline__ u16 f2b(float f) {
  union { float f; unsigned int i; } c; c.f = f;
  unsigned int r = c.i + 0x7fffu + ((c.i >> 16) & 1u);
  return (u16)(r >> 16);
}
__device__ __forceinline__ void gl_lds16(const u16* g, u16* l) {
  __builtin_amdgcn_global_load_lds(
      (const __attribute__((address_space(1))) unsigned int*)g,
      (__attribute__((address_space(3))) unsigned int*)l, 16, 0, 0);
}

// ---------------- Stage 0: fp32 -> bf16 conversion ----------------
struct CvtArgs {
  const float* src[5];
  u16* dst[5];
};
#define G0 (XELEMS / 4)
#define GW (WELEMS / 4)
#define GTOT (G0 + 4 * GW)

__global__ __launch_bounds__(256) void cvt_kernel(CvtArgs a) {
  size_t g = (size_t)blockIdx.x * 256 + threadIdx.x;
  if (g >= GTOT) return;
  int t; size_t off;
  if (g < G0) { t = 0; off = g; }
  else { size_t r = g - G0; t = 1 + (int)(r / GW); off = r % GW; }
  f4 v = *(const f4*)(a.src[t] + off * 4);
  us4 o;
  o[0] = f2b(v[0]); o[1] = f2b(v[1]); o[2] = f2b(v[2]); o[3] = f2b(v[3]);
  *(us4*)(a.dst[t] + off * 4) = o;
}

// ---------------- Stage 1: QKV projection (BM=128, BN=128, BK=64, dbuf, 2 blocks/CU) ----------------
// Grid 1152 (64 bm x 18 bn), 256 threads (4 waves as 2M x 2N; wave = 64x64 out).
// Per iter per wave: 8 gl_lds (stage t+1), 16 ds_read_b128, 32 MFMA, 1 __syncthreads.
// The end-of-iter barrier's implied vmcnt(0) drains loads that flew during compute
// (catalog 2-phase recipe). 2 blocks/CU cover each other's drain stalls.
// L2-blocked XCD swizzle: xcd gets 8 bm x 18 bn, ordered (bn-group of 6) x bm8 x bn6:
// resident working set ~ 8 x-panels (1.5 MB) + 6 W-slices (1.2 MB) < 4 MB L2.
__global__ __launch_bounds__(256, 2) void qkv_gemm(
    const u16* __restrict__ x, const u16* __restrict__ Wq,
    const u16* __restrict__ Wk, const u16* __restrict__ Wv,
    u16* __restrict__ q, u16* __restrict__ k, u16* __restrict__ vt)
{
  __shared__ __align__(16) u16 lA[2][128 * 64];   // 16 KB x2
  __shared__ __align__(16) u16 lB[2][128 * 64];   // 16 KB x2   total 64 KB

  const int tid  = threadIdx.x;
  const int lane = tid & 63;
  const int w    = tid >> 6;        // 0..3
  const int wm   = w >> 1;          // 0..1
  const int wn   = w & 1;           // 0..1
  const int col  = lane & 15;
  const int quad = lane >> 4;

  // L2-blocked XCD swizzle: bid -> (xcd, j); j = bng*48 + bm8*6 + bn6
  const int bid = blockIdx.x;
  const int xcd = bid & 7;
  const int j   = bid >> 3;         // 0..143
  const int bng = j / 48;           // 0..2
  const int rr  = j % 48;
  const int bm8 = rr / 6;           // 0..7
  const int bn6 = rr % 6;           // 0..5
  const int bm  = xcd * 8 + bm8;    // 0..63
  const int bn  = bng * 6 + bn6;    // 0..17

  const int m0 = bm * 128;
  const int proj = bn / 6;                      // 0=q,1=k,2=v
  const u16* Wsel = (proj == 0) ? Wq : (proj == 1 ? Wk : Wv);
  const int nrem0 = (bn % 6) * 128;

  const int srow8 = lane >> 3;                  // 0..7
  const int sg    = (lane & 7) ^ srow8;         // pre-swizzled source granule

  // wave w stages A rows [w*32, w*32+32) and B rows [w*32, w*32+32), 4 gl_lds each
  const u16* gA = x    + (size_t)(m0    + w * 32 + srow8) * DMODEL + sg * 8;
  const u16* gB = Wsel + (size_t)(nrem0 + w * 32 + srow8) * DMODEL + sg * 8;

  f4 acc[4][4];
#pragma unroll
  for (int i = 0; i < 4; i++)
#pragma unroll
    for (int jj = 0; jj < 4; jj++) acc[i][jj] = (f4)0.0f;

#define QKV_STAGE(T, BUF)                                                      \
  do {                                                                         \
    const int kk_ = (T) * 64;                                                  \
    _Pragma("unroll")                                                          \
    for (int i_ = 0; i_ < 4; i_++)                                             \
      gl_lds16(gA + (size_t)(i_ * 8) * DMODEL + kk_,                           \
               &lA[BUF][(w * 32 + i_ * 8) * 64]);                              \
    _Pragma("unroll")                                                          \
    for (int i_ = 0; i_ < 4; i_++)                                             \
      gl_lds16(gB + (size_t)(i_ * 8) * DMODEL + kk_,                           \
               &lB[BUF][(w * 32 + i_ * 8) * 64]);                              \
  } while (0)

  // prologue: tile 0 staged and drained
  QKV_STAGE(0, 0);
  __syncthreads();

  for (int t = 0; t < 12; t++) {
    const int cur = t & 1;
    // stage t+1 FIRST: its flight overlaps this iter's compute; the buffer it
    // overwrites (tile t-1) was freed by the barrier at end of iter t-1.
    if (t < 11) QKV_STAGE(t + 1, cur ^ 1);

    bf8 af[4][2], bfr[4][2];
#pragma unroll
    for (int mt = 0; mt < 4; mt++) {
      const int row = wm * 64 + mt * 16 + col;
#pragma unroll
      for (int kt = 0; kt < 2; kt++)
        af[mt][kt] = *(const bf8*)&lA[cur][row * 64 + (((kt * 4 + quad) ^ (row & 7)) << 3)];
    }
#pragma unroll
    for (int nt = 0; nt < 4; nt++) {
      const int row = wn * 64 + nt * 16 + col;
#pragma unroll
      for (int kt = 0; kt < 2; kt++)
        bfr[nt][kt] = *(const bf8*)&lB[cur][row * 64 + (((kt * 4 + quad) ^ (row & 7)) << 3)];
    }

    __builtin_amdgcn_s_setprio(1);
#pragma unroll
    for (int mt = 0; mt < 4; mt++)
#pragma unroll
      for (int nt = 0; nt < 4; nt++)
#pragma unroll
        for (int kt = 0; kt < 2; kt++)
          acc[mt][nt] = __builtin_amdgcn_mfma_f32_16x16x32_bf16(af[mt][kt], bfr[nt][kt], acc[mt][nt], 0, 0, 0);
    __builtin_amdgcn_s_setprio(0);

    // implied vmcnt(0)+lgkmcnt(0)+barrier: tile t+1 resident, buf[cur] freed
    __syncthreads();
  }
#undef QKV_STAGE

  const int mw0 = m0 + wm * 64, nw0 = nrem0 + wn * 64;
  if (proj == 2) {
    // V^T: [b][h][e][tok]; lane's 4 acc rows are consecutive tok -> one us4 store
#pragma unroll
    for (int mt = 0; mt < 4; mt++) {
#pragma unroll
      for (int nt = 0; nt < 4; nt++) {
        const int nc = nw0 + nt * 16 + col;
        const int h = nc >> 6, e = nc & 63;
        const int t0 = mw0 + mt * 16 + quad * 4;
        const int b = t0 >> 10, tok0 = t0 & 1023;
        us4 pk;
#pragma unroll
        for (int r = 0; r < 4; r++) pk[r] = f2b(acc[mt][nt][r]);
        *(us4*)(vt + ((size_t)(b * NHEAD + h) * DHEAD + e) * NSEQ + tok0) = pk;
      }
    }
  } else {
    u16* dst = (proj == 0) ? q : k;
#pragma unroll
    for (int mt = 0; mt < 4; mt++) {
#pragma unroll
      for (int nt = 0; nt < 4; nt++) {
        const int nc = nw0 + nt * 16 + col;
        const int h = nc >> 6, e = nc & 63;
#pragma unroll
        for (int r = 0; r < 4; r++) {
          const int t = mw0 + mt * 16 + quad * 4 + r;
          const int b = t >> 10, tok = t & 1023;
          dst[((size_t)(b * NHEAD + h) * NSEQ + tok) * DHEAD + e] = f2b(acc[mt][nt][r]);
        }
      }
    }
  }
}

// ---------------- Stage 2: flash attention (swapped QK^T, packed P, dbuf K/V) ----------------
// 1D grid 768: idx = qc*96 + bh  ->  idx%8 == bh%8, all q-chunks of one (b,h) on one XCD.
// S^T = mfma(K, Q): lane holds (q = col, kv = kvt*16 + quad*4 + r)  => kv runs are
// lane-local: pack 4 bf16 with f2b and store ONE ds_write_b64 at ldsP[w][q][kv].
// PV A-frag (m = q = lane&15, k = kv = quad*8+j) = single aligned ds_read_b128.
__global__ __launch_bounds__(256, 3) void attn_kernel(
    const u16* __restrict__ q, const u16* __restrict__ k,
    const u16* __restrict__ vt, u16* __restrict__ attn)
{
  __shared__ __align__(16) u16 ldsK[2][64 * 64];  // K tile [64 kv][64 e], swizzled, 8 KB x2
  __shared__ __align__(16) u16 ldsV[2][64 * 64];  // V^T tile [64 e][64 kv], swizzled, 8 KB x2
  __shared__ __align__(16) u16 ldsP[4][32][72];   // wave-private P [q-row][kv], stride-72 (18 KB)

  const int tid  = threadIdx.x;
  const int lane = tid & 63;
  const int w    = tid >> 6;
  const int col  = lane & 15;
  const int quad = lane >> 4;

  const int idx = blockIdx.x;
  const int bh = idx % 96, qc = idx / 96;
  const int b = bh / 12, h = bh % 12;

  const size_t head = ((size_t)b * NHEAD + h) * NSEQ * DHEAD;  // works for q,k and vt
  const int q0 = qc * 128 + w * 32;

  const int srow8 = lane >> 3;                // 0..7 row within an 8-row chunk
  const int sg    = (lane & 7) ^ srow8;       // swizzled source granule

  // ones B-frag for l row-sums via MFMA
  bf8 onesf;
#pragma unroll
  for (int jj = 0; jj < 8; jj++) onesf[jj] = (short)0x3F80;  // bf16 1.0

  // Q fragments, pre-scaled by 1/sqrt(64)=0.125 (exact in bf16)
  bf8 qf[2][2];
#pragma unroll
  for (int qt = 0; qt < 2; qt++)
#pragma unroll
    for (int kt = 0; kt < 2; kt++) {
      const int row = q0 + qt * 16 + col;
      bf8 t = *(const bf8*)(q + head + (size_t)row * DHEAD + kt * 32 + quad * 8);
#pragma unroll
      for (int jj = 0; jj < 8; jj++) t[jj] = (short)f2b(b2f((u16)t[jj]) * 0.125f);
      qf[qt][kt] = t;
    }

  f4 lacc[2];
  f4 o[2][4];
#pragma unroll
  for (int mt = 0; mt < 2; mt++) {
    lacc[mt] = (f4)0.0f;
#pragma unroll
    for (int et = 0; et < 4; et++) o[mt][et] = (f4)0.0f;
  }

  // prologue: stage tile 0 into buffer 0
#pragma unroll
  for (int i = 0; i < 2; i++) {
    const int li = w * 2 + i;
    gl_lds16(k  + head + (size_t)(li * 8 + srow8) * DHEAD + sg * 8, &ldsK[0][li * 512]);
    gl_lds16(vt + head + (size_t)(li * 8 + srow8) * NSEQ + sg * 8,  &ldsV[0][li * 512]);
  }

  for (int t = 0; t < NSEQ / 64; t++) {
    const int cur = t & 1;
    __syncthreads();   // drains tile-t loads; guards reuse of the other buffer
    if (t < NSEQ / 64 - 1) {
      const int kb2 = (t + 1) * 64;
#pragma unroll
      for (int i = 0; i < 2; i++) {
        const int li = w * 2 + i;
        gl_lds16(k  + head + (size_t)(kb2 + li * 8 + srow8) * DHEAD + sg * 8,
                 &ldsK[cur ^ 1][li * 512]);
        gl_lds16(vt + head + (size_t)(li * 8 + srow8) * NSEQ + kb2 + sg * 8,
                 &ldsV[cur ^ 1][li * 512]);
      }
    }

    // S^T = K @ (Q/8)^T  [64 kv x 32 q] per wave; lane: q = col, kv = kvt*16+quad*4+r
    f4 st[4][2];
#pragma unroll
    for (int kvt = 0; kvt < 4; kvt++)
#pragma unroll
      for (int qt = 0; qt < 2; qt++) st[kvt][qt] = (f4)0.0f;
#pragma unroll
    for (int kt = 0; kt < 2; kt++) {
      bf8 kf[4];
#pragma unroll
      for (int kvt = 0; kvt < 4; kvt++) {
        const int row = kvt * 16 + col;
        kf[kvt] = *(const bf8*)&ldsK[cur][row * 64 + (((kt * 4 + quad) ^ (col & 7)) << 3)];
      }
      __builtin_amdgcn_s_setprio(1);
#pragma unroll
      for (int kvt = 0; kvt < 4; kvt++)
#pragma unroll
        for (int qt = 0; qt < 2; qt++)
          st[kvt][qt] = __builtin_amdgcn_mfma_f32_16x16x32_bf16(kf[kvt], qf[qt][kt], st[kvt][qt], 0, 0, 0);
      __builtin_amdgcn_s_setprio(0);
    }

    // P = exp(S): f2b (proven bit-ops RNE) packed in-register, ONE ds_write_b64 per acc
#pragma unroll
    for (int kvt = 0; kvt < 4; kvt++)
#pragma unroll
      for (int qt = 0; qt < 2; qt++) {
        const f4 p = st[kvt][qt];
        bf4 pw;
        pw[0] = (short)f2b(__expf(p[0]));
        pw[1] = (short)f2b(__expf(p[1]));
        pw[2] = (short)f2b(__expf(p[2]));
        pw[3] = (short)f2b(__expf(p[3]));
        *(bf4*)&ldsP[w][qt * 16 + col][kvt * 16 + quad * 4] = pw;
      }
    asm volatile("" ::: "memory");   // order P writes before PV reads (aliasing guard)

    // PV: vf hoisted (shared by both mt); pf = one conflict-free ds_read_b128
#pragma unroll
    for (int kt2 = 0; kt2 < 2; kt2++) {
      bf8 vf[4];
#pragma unroll
      for (int et = 0; et < 4; et++) {
        const int row = et * 16 + col;
        vf[et] = *(const bf8*)&ldsV[cur][row * 64 + (((kt2 * 4 + quad) ^ (col & 7)) << 3)];
      }
#pragma unroll
      for (int mt = 0; mt < 2; mt++) {
        const bf8 pf = *(const bf8*)&ldsP[w][mt * 16 + col][kt2 * 32 + quad * 8];
        __builtin_amdgcn_s_setprio(1);
        lacc[mt] = __builtin_amdgcn_mfma_f32_16x16x32_bf16(pf, onesf, lacc[mt], 0, 0, 0);
#pragma unroll
        for (int et = 0; et < 4; et++)
          o[mt][et] = __builtin_amdgcn_mfma_f32_16x16x32_bf16(pf, vf[et], o[mt][et], 0, 0, 0);
        __builtin_amdgcn_s_setprio(0);
      }
    }
  }

  // epilogue: every lane already holds its row-sum in lacc (all n-cols equal)
#pragma unroll
  for (int mt = 0; mt < 2; mt++)
#pragma unroll
    for (int r = 0; r < 4; r++) {
      const float inv = 1.0f / lacc[mt][r];
      const int token = q0 + mt * 16 + quad * 4 + r;
#pragma unroll
      for (int et = 0; et < 4; et++)
        attn[(size_t)(b * NSEQ + token) * DMODEL + h * DHEAD + et * 16 + col] =
            f2b(o[mt][et][r] * inv);
    }
}

// ---------------- Stage 3: output projection + bias (r0-proven: 128^2, BK=32, dbuf) ----------------
__global__ __launch_bounds__(256, 4) void out_gemm(
    const u16* __restrict__ attn, const u16* __restrict__ Wo,
    const float* __restrict__ bo, float* __restrict__ out)
{
  __shared__ __align__(16) u16 lA[2][128 * 32];
  __shared__ __align__(16) u16 lB[2][128 * 32];

  const int tid  = threadIdx.x;
  const int lane = tid & 63;
  const int w    = tid >> 6;
  const int wm   = w >> 1, wn = w & 1;
  const int col  = lane & 15;
  const int quad = lane >> 4;
  const int bm = blockIdx.x;   // 0..63
  const int bn = blockIdx.y;   // 0..5

  const int m0 = bm * 128;
  const int n0 = bn * 128;

  const int srow = lane >> 2;
  const int sg   = (lane & 3) ^ ((srow >> 1) & 3);
  const u16* gA0 = attn + (size_t)(m0 + w * 32 + srow) * DMODEL + sg * 8;
  const u16* gB0 = Wo   + (size_t)(n0 + w * 32 + srow) * DMODEL + sg * 8;

  f4 acc[4][4];
#pragma unroll
  for (int i = 0; i < 4; i++)
#pragma unroll
    for (int jj = 0; jj < 4; jj++) acc[i][jj] = (f4)0.0f;

  gl_lds16(gA0, &lA[0][(w * 32) * 32]);
  gl_lds16(gA0 + (size_t)16 * DMODEL, &lA[0][(w * 32 + 16) * 32]);
  gl_lds16(gB0, &lB[0][(w * 32) * 32]);
  gl_lds16(gB0 + (size_t)16 * DMODEL, &lB[0][(w * 32 + 16) * 32]);

  for (int it = 0; it < 24; it++) {
    const int cur = it & 1;
    __syncthreads();
    if (it < 23) {
      const int kk = (it + 1) * 32;
      gl_lds16(gA0 + kk, &lA[cur ^ 1][(w * 32) * 32]);
      gl_lds16(gA0 + (size_t)16 * DMODEL + kk, &lA[cur ^ 1][(w * 32 + 16) * 32]);
      gl_lds16(gB0 + kk, &lB[cur ^ 1][(w * 32) * 32]);
      gl_lds16(gB0 + (size_t)16 * DMODEL + kk, &lB[cur ^ 1][(w * 32 + 16) * 32]);
    }

    bf8 af[4], bfr[4];
#pragma unroll
    for (int mt = 0; mt < 4; mt++) {
      const int row = wm * 64 + mt * 16 + col;
      af[mt] = *(const bf8*)&lA[cur][row * 32 + ((quad ^ ((row >> 1) & 3)) << 3)];
    }
#pragma unroll
    for (int nt = 0; nt < 4; nt++) {
      const int row = wn * 64 + nt * 16 + col;
      bfr[nt] = *(const bf8*)&lB[cur][row * 32 + ((quad ^ ((row >> 1) & 3)) << 3)];
    }
#pragma unroll
    for (int mt = 0; mt < 4; mt++)
#pragma unroll
      for (int nt = 0; nt < 4; nt++)
        acc[mt][nt] = __builtin_amdgcn_mfma_f32_16x16x32_bf16(af[mt], bfr[nt], acc[mt][nt], 0, 0, 0);
  }

  const int mw0 = m0 + wm * 64, nw0 = n0 + wn * 64;
#pragma unroll
  for (int mt = 0; mt < 4; mt++)
#pragma unroll
    for (int nt = 0; nt < 4; nt++) {
      const int n = nw0 + nt * 16 + col;
      const float bias = bo[n];
#pragma unroll
      for (int r = 0; r < 4; r++) {
        const int row = mw0 + mt * 16 + quad * 4 + r;
        out[(size_t)row * DMODEL + n] = acc[mt][nt][r] + bias;
      }
    }
}

extern "C" void kernel_launch(void* const* d_in, const int* in_sizes, int n_in,
                              void* d_out, int out_size, void* d_ws, size_t ws_size,
                              hipStream_t stream) {
  const float* x  = (const float*)d_in[0];
  const float* Wq = (const float*)d_in[1];
  const float* Wk = (const float*)d_in[2];
  const float* Wv = (const float*)d_in[3];
  const float* Wo = (const float*)d_in[4];
  const float* bo = (const float*)d_in[5];
  float* out = (float*)d_out;

  u16* xb   = (u16*)d_ws;
  u16* wqb  = xb  + XELEMS;
  u16* wkb  = wqb + WELEMS;
  u16* wvb  = wkb + WELEMS;
  u16* wob  = wvb + WELEMS;
  u16* q    = wob + WELEMS;
  u16* k    = q   + XELEMS;
  u16* vt   = k   + XELEMS;
  u16* attn = vt  + XELEMS;

  CvtArgs ca;
  ca.src[0] = x;  ca.src[1] = Wq;  ca.src[2] = Wk;  ca.src[3] = Wv;  ca.src[4] = Wo;
  ca.dst[0] = xb; ca.dst[1] = wqb; ca.dst[2] = wkb; ca.dst[3] = wvb; ca.dst[4] = wob;

  cvt_kernel<<<dim3((GTOT + 255) / 256), 256, 0, stream>>>(ca);
  qkv_gemm<<<dim3(1152), 256, 0, stream>>>(xb, wqb, wkb, wvb, q, k, vt);
  attn_kernel<<<dim3(768), 256, 0, stream>>>(q, k, vt, attn);
  out_gemm<<<dim3(64, 6), 256, 0, stream>>>(attn, wob, bo, out);
}